// Round 1
// baseline (427.463 us; speedup 1.0000x reference)
//
#include <hip/hip_runtime.h>
#include <stdint.h>
#include <math.h>

#define B_ 8
#define S_ 1024
#define D0_ 128
#define D_ 256
#define H_ 8
#define HD_ 32
#define BH_ (B_*H_)

typedef __attribute__((ext_vector_type(8))) short short8;
typedef __attribute__((ext_vector_type(4))) float f32x4;

__device__ __forceinline__ unsigned short f2bf(float x) {
    unsigned int u = __float_as_uint(x);
    u += 0x7FFFu + ((u >> 16) & 1u);
    return (unsigned short)(u >> 16);
}
__device__ __forceinline__ float bf2f(unsigned short s) {
    return __uint_as_float(((unsigned int)s) << 16);
}

// ---------------- Kernel 1: projections (fp32 VALU GEMM) ----------------
// y[M=8192][N=256] = x[8192][128] @ W[256][128]^T ; epilogue splits to bf16 hi/lo
// z=0: Q (hi/lo), z=1: K (hi/lo), z=2: V (single bf16, stored transposed [bh][d][s])
__global__ __launch_bounds__(256) void proj_kernel(
    const float* __restrict__ query,
    const float* __restrict__ Wq, const float* __restrict__ Wk, const float* __restrict__ Wv,
    unsigned short* __restrict__ Qhi, unsigned short* __restrict__ Qlo,
    unsigned short* __restrict__ Khi, unsigned short* __restrict__ Klo,
    unsigned short* __restrict__ Vt)
{
    const int z = blockIdx.z;
    const float* W = (z == 0) ? Wq : (z == 1) ? Wk : Wv;
    const int m0 = blockIdx.x * 64;
    const int n0 = blockIdx.y * 64;
    __shared__ float xs[64 * 68];
    __shared__ float ws[64 * 68];
    const int t = threadIdx.x;
    const int ty = t >> 4, tx = t & 15;
    float acc[4][4] = {};
    for (int kc = 0; kc < 128; kc += 64) {
        #pragma unroll
        for (int it = 0; it < 4; ++it) {
            int fi = t + it * 256;
            int row = fi >> 4, c4 = fi & 15;
            *(float4*)(&xs[row * 68 + c4 * 4]) = *(const float4*)(&query[(size_t)(m0 + row) * 128 + kc + c4 * 4]);
            *(float4*)(&ws[row * 68 + c4 * 4]) = *(const float4*)(&W[(size_t)(n0 + row) * 128 + kc + c4 * 4]);
        }
        __syncthreads();
        #pragma unroll
        for (int k4 = 0; k4 < 16; ++k4) {
            float4 a4[4], b4[4];
            #pragma unroll
            for (int i = 0; i < 4; ++i) a4[i] = *(const float4*)(&xs[(ty * 4 + i) * 68 + k4 * 4]);
            #pragma unroll
            for (int j = 0; j < 4; ++j) b4[j] = *(const float4*)(&ws[(tx * 4 + j) * 68 + k4 * 4]);
            #pragma unroll
            for (int i = 0; i < 4; ++i)
                #pragma unroll
                for (int j = 0; j < 4; ++j)
                    acc[i][j] += a4[i].x * b4[j].x + a4[i].y * b4[j].y + a4[i].z * b4[j].z + a4[i].w * b4[j].w;
        }
        __syncthreads();
    }
    #pragma unroll
    for (int i = 0; i < 4; ++i) {
        int m = m0 + ty * 4 + i;
        int b = m >> 10, s = m & 1023;
        #pragma unroll
        for (int j = 0; j < 4; ++j) {
            int o = n0 + tx * 4 + j;
            int h = o >> 5, d = o & 31;
            int bh = b * 8 + h;
            float y = acc[i][j];
            if (z < 2) {
                unsigned short hi = f2bf(y);
                unsigned short lo = f2bf(y - bf2f(hi));
                size_t idx = ((size_t)(bh * 1024 + s)) * 32 + d;
                if (z == 0) { Qhi[idx] = hi; Qlo[idx] = lo; }
                else        { Khi[idx] = hi; Klo[idx] = lo; }
            } else {
                Vt[((size_t)(bh * 32 + d)) * 1024 + s] = f2bf(y);
            }
        }
    }
}

// ---------------- Kernel 1b: mask bias from Q row sums ----------------
__global__ void mask_kernel(const unsigned short* __restrict__ Qhi,
                            const unsigned short* __restrict__ Qlo,
                            float* __restrict__ maskbias)
{
    int r = blockIdx.x * blockDim.x + threadIdx.x;
    if (r >= BH_ * S_) return;
    const unsigned short* ph = Qhi + (size_t)r * 32;
    const unsigned short* pl = Qlo + (size_t)r * 32;
    float s = 0.f;
    #pragma unroll
    for (int d = 0; d < 32; ++d) s += bf2f(ph[d]) + bf2f(pl[d]);
    maskbias[r] = (s != 0.0f) ? 0.0f : -INFINITY;
}

// ---------------- Kernel 2: fused attention ----------------
// grid 2048 = 64 (b,h) x 32 q-tiles; block 256 = 4 waves.
// Wave w owns key strip [256w, 256w+256): scores kept in regs (2 qf x 16 kf x f32x4).
// P (bf16 attn) staged in LDS for the PV A-operand transpose; wave w computes
// out fragment (qf = w>>1, df = w&1) over the full 1024-key depth.
#define ATTN_LDS (32 * 1032 * 2 + 2 * 128 * 4)
__global__ __launch_bounds__(256, 2) void attn_kernel(
    const unsigned short* __restrict__ Qhi, const unsigned short* __restrict__ Qlo,
    const unsigned short* __restrict__ Khi, const unsigned short* __restrict__ Klo,
    const unsigned short* __restrict__ Vt, const float* __restrict__ maskbias,
    const float* __restrict__ U, float* __restrict__ attn_out, float* __restrict__ out_buf)
{
    extern __shared__ unsigned char lds_raw[];
    unsigned short* P = (unsigned short*)lds_raw;            // [32][1032] bf16
    float* red1 = (float*)(lds_raw + 32 * 1032 * 2);         // [4][32]
    float* red2 = red1 + 128;                                // [4][32]

    const int bh = blockIdx.x >> 5;
    const int qbase = (blockIdx.x & 31) << 5;
    const int tid = threadIdx.x;
    const int wid = tid >> 6;
    const int c = tid & 15;
    const int g = (tid >> 4) & 3;
    const int kstrip = wid << 8;

    const size_t bh_qk = (size_t)bh * S_ * 32;
    const size_t bh_u = (size_t)bh * S_ * S_;

    // Q fragments (A operand), hi & lo
    short8 qh[2], ql[2];
    #pragma unroll
    for (int qf = 0; qf < 2; ++qf) {
        size_t off = bh_qk + (size_t)(qbase + qf * 16 + c) * 32 + 8 * g;
        qh[qf] = *(const short8*)(Qhi + off);
        ql[qf] = *(const short8*)(Qlo + off);
    }

    f32x4 s[2][16];
    #pragma unroll
    for (int qf = 0; qf < 2; ++qf)
        #pragma unroll
        for (int kf = 0; kf < 16; ++kf)
            s[qf][kf] = (f32x4){0.f, 0.f, 0.f, 0.f};

    // QK^T via split bf16 MFMA: hi*hi + lo*hi + hi*lo
    #pragma unroll
    for (int kf = 0; kf < 16; ++kf) {
        size_t koff = bh_qk + (size_t)(kstrip + kf * 16 + c) * 32 + 8 * g;
        short8 kh = *(const short8*)(Khi + koff);
        short8 kl = *(const short8*)(Klo + koff);
        #pragma unroll
        for (int qf = 0; qf < 2; ++qf) {
            s[qf][kf] = __builtin_amdgcn_mfma_f32_16x16x32_bf16(qh[qf], kh, s[qf][kf], 0, 0, 0);
            s[qf][kf] = __builtin_amdgcn_mfma_f32_16x16x32_bf16(ql[qf], kh, s[qf][kf], 0, 0, 0);
            s[qf][kf] = __builtin_amdgcn_mfma_f32_16x16x32_bf16(qh[qf], kl, s[qf][kf], 0, 0, 0);
        }
    }

    const float inv_scale = 0.17677669529663687f; // 1/sqrt(32)
    // add U, scale, mask
    #pragma unroll
    for (int kf = 0; kf < 16; ++kf) {
        int k = kstrip + kf * 16 + c;
        float mbv = maskbias[bh * S_ + k];
        #pragma unroll
        for (int qf = 0; qf < 2; ++qf) {
            #pragma unroll
            for (int r = 0; r < 4; ++r) {
                int q = qbase + qf * 16 + g * 4 + r;
                float u = U[bh_u + (size_t)q * S_ + k];
                s[qf][kf][r] = (s[qf][kf][r] + u) * inv_scale + mbv;
            }
        }
    }

    // row max (per-lane over kf, then across the 16 c-lanes)
    float mx[2][4];
    #pragma unroll
    for (int qf = 0; qf < 2; ++qf)
        #pragma unroll
        for (int r = 0; r < 4; ++r) {
            float m = s[qf][0][r];
            #pragma unroll
            for (int kf = 1; kf < 16; ++kf) m = fmaxf(m, s[qf][kf][r]);
            #pragma unroll
            for (int off = 1; off < 16; off <<= 1) m = fmaxf(m, __shfl_xor(m, off, 64));
            mx[qf][r] = m;
        }
    if (c == 0) {
        #pragma unroll
        for (int qf = 0; qf < 2; ++qf)
            #pragma unroll
            for (int r = 0; r < 4; ++r)
                red1[wid * 32 + qf * 16 + g * 4 + r] = mx[qf][r];
    }
    __syncthreads();

    float gm[2][4];
    #pragma unroll
    for (int qf = 0; qf < 2; ++qf)
        #pragma unroll
        for (int r = 0; r < 4; ++r) {
            int row = qf * 16 + g * 4 + r;
            gm[qf][r] = fmaxf(fmaxf(red1[row], red1[32 + row]), fmaxf(red1[64 + row], red1[96 + row]));
        }

    // exp & sum
    float sm[2][4];
    #pragma unroll
    for (int qf = 0; qf < 2; ++qf)
        #pragma unroll
        for (int r = 0; r < 4; ++r) {
            float acc = 0.f;
            #pragma unroll
            for (int kf = 0; kf < 16; ++kf) {
                float p = __expf(s[qf][kf][r] - gm[qf][r]);
                s[qf][kf][r] = p;
                acc += p;
            }
            #pragma unroll
            for (int off = 1; off < 16; off <<= 1) acc += __shfl_xor(acc, off, 64);
            sm[qf][r] = acc;
        }
    if (c == 0) {
        #pragma unroll
        for (int qf = 0; qf < 2; ++qf)
            #pragma unroll
            for (int r = 0; r < 4; ++r)
                red2[wid * 32 + qf * 16 + g * 4 + r] = sm[qf][r];
    }
    __syncthreads();

    float inv[2][4];
    #pragma unroll
    for (int qf = 0; qf < 2; ++qf)
        #pragma unroll
        for (int r = 0; r < 4; ++r) {
            int row = qf * 16 + g * 4 + r;
            float ssum = red2[row] + red2[32 + row] + red2[64 + row] + red2[96 + row];
            inv[qf][r] = 1.0f / ssum;
        }

    // normalize: write attn (f32, global) and P (bf16, LDS)
    #pragma unroll
    for (int kf = 0; kf < 16; ++kf) {
        int k = kstrip + kf * 16 + c;
        #pragma unroll
        for (int qf = 0; qf < 2; ++qf) {
            #pragma unroll
            for (int r = 0; r < 4; ++r) {
                int row = qf * 16 + g * 4 + r;
                float a = s[qf][kf][r] * inv[qf][r];
                attn_out[bh_u + (size_t)(qbase + row) * S_ + k] = a;
                P[row * 1032 + k] = f2bf(a);
            }
        }
    }
    __syncthreads();

    // PV: wave (pqf, df) fragment over full 1024 depth
    const int df = wid & 1, pqf = wid >> 1;
    f32x4 o = (f32x4){0.f, 0.f, 0.f, 0.f};
    const unsigned short* vbase = Vt + (size_t)(bh * 32 + df * 16 + c) * S_;
    #pragma unroll
    for (int st = 0; st < 32; ++st) {
        short8 A = *(const short8*)(P + (pqf * 16 + c) * 1032 + st * 32 + 8 * g);
        short8 Bv = *(const short8*)(vbase + st * 32 + 8 * g);
        o = __builtin_amdgcn_mfma_f32_16x16x32_bf16(A, Bv, o, 0, 0, 0);
    }
    const int b = bh >> 3, h = bh & 7;
    #pragma unroll
    for (int r = 0; r < 4; ++r) {
        int srow = qbase + pqf * 16 + g * 4 + r;
        out_buf[((size_t)(b * 1024 + srow)) * 256 + h * 32 + df * 16 + c] = o[r];
    }
}

// ---------------- Kernel 3: output projection ----------------
// output[8192][128] = out[8192][256] @ Wo[128][256]^T (fp32 VALU)
__global__ __launch_bounds__(256) void outproj_kernel(
    const float* __restrict__ xb, const float* __restrict__ Wo, float* __restrict__ outp)
{
    const int m0 = blockIdx.x * 64;
    const int n0 = blockIdx.y * 64;
    __shared__ float xs[64 * 68];
    __shared__ float ws[64 * 68];
    const int t = threadIdx.x;
    const int ty = t >> 4, tx = t & 15;
    float acc[4][4] = {};
    for (int kc = 0; kc < 256; kc += 64) {
        #pragma unroll
        for (int it = 0; it < 4; ++it) {
            int fi = t + it * 256;
            int row = fi >> 4, c4 = fi & 15;
            *(float4*)(&xs[row * 68 + c4 * 4]) = *(const float4*)(&xb[(size_t)(m0 + row) * 256 + kc + c4 * 4]);
            *(float4*)(&ws[row * 68 + c4 * 4]) = *(const float4*)(&Wo[(size_t)(n0 + row) * 256 + kc + c4 * 4]);
        }
        __syncthreads();
        #pragma unroll
        for (int k4 = 0; k4 < 16; ++k4) {
            float4 a4[4], b4[4];
            #pragma unroll
            for (int i = 0; i < 4; ++i) a4[i] = *(const float4*)(&xs[(ty * 4 + i) * 68 + k4 * 4]);
            #pragma unroll
            for (int j = 0; j < 4; ++j) b4[j] = *(const float4*)(&ws[(tx * 4 + j) * 68 + k4 * 4]);
            #pragma unroll
            for (int i = 0; i < 4; ++i)
                #pragma unroll
                for (int j = 0; j < 4; ++j)
                    acc[i][j] += a4[i].x * b4[j].x + a4[i].y * b4[j].y + a4[i].z * b4[j].z + a4[i].w * b4[j].w;
        }
        __syncthreads();
    }
    #pragma unroll
    for (int i = 0; i < 4; ++i)
        #pragma unroll
        for (int j = 0; j < 4; ++j)
            outp[(size_t)(m0 + ty * 4 + i) * 128 + n0 + tx * 4 + j] = acc[i][j];
}

extern "C" void kernel_launch(void* const* d_in, const int* in_sizes, int n_in,
                              void* d_out, int out_size, void* d_ws, size_t ws_size,
                              hipStream_t stream)
{
    const float* query = (const float*)d_in[0];
    const float* U     = (const float*)d_in[1];
    const float* Wq    = (const float*)d_in[2];
    const float* Wk    = (const float*)d_in[3];
    const float* Wv    = (const float*)d_in[4];
    const float* Wo    = (const float*)d_in[5];

    float* output = (float*)d_out;                                 // B*S*D0
    float* attn   = (float*)d_out + (size_t)B_ * S_ * D0_;         // B*H*S*S

    const size_t NQK = (size_t)BH_ * S_ * 32; // 2,097,152 elements
    unsigned short* Qhi = (unsigned short*)d_ws;
    unsigned short* Qlo = Qhi + NQK;
    unsigned short* Khi = Qlo + NQK;
    unsigned short* Klo = Khi + NQK;
    unsigned short* Vt  = Klo + NQK;
    float* maskbias = (float*)(Vt + NQK);            // BH*S floats
    float* out_buf  = maskbias + (size_t)BH_ * S_;   // 8192*256 floats

    proj_kernel<<<dim3(128, 4, 3), 256, 0, stream>>>(query, Wq, Wk, Wv, Qhi, Qlo, Khi, Klo, Vt);
    mask_kernel<<<dim3(256), 256, 0, stream>>>(Qhi, Qlo, maskbias);

    hipFuncSetAttribute(reinterpret_cast<const void*>(attn_kernel),
                        hipFuncAttributeMaxDynamicSharedMemorySize, ATTN_LDS);
    attn_kernel<<<dim3(2048), 256, ATTN_LDS, stream>>>(Qhi, Qlo, Khi, Klo, Vt, maskbias, U, attn, out_buf);

    outproj_kernel<<<dim3(128, 2), 256, 0, stream>>>(out_buf, Wo, output);
}

// Round 2
// 275.443 us; speedup vs baseline: 1.5519x; 1.5519x over previous
//
#include <hip/hip_runtime.h>
#include <stdint.h>
#include <math.h>

#define B_ 8
#define S_ 1024
#define D0_ 128
#define D_ 256
#define H_ 8
#define HD_ 32
#define BH_ (B_*H_)

typedef __attribute__((ext_vector_type(8))) short short8;
typedef __attribute__((ext_vector_type(4))) float f32x4;
typedef __attribute__((ext_vector_type(4))) unsigned int u32x4;
typedef __attribute__((ext_vector_type(2))) unsigned int u32x2;
typedef __attribute__((ext_vector_type(2))) float f32x2;

__device__ __forceinline__ unsigned short f2bf(float x) {
    unsigned int u = __float_as_uint(x);
    u += 0x7FFFu + ((u >> 16) & 1u);
    return (unsigned short)(u >> 16);
}
__device__ __forceinline__ float bf2f(unsigned short s) {
    return __uint_as_float(((unsigned int)s) << 16);
}

// ---------------- Kernel 1: projections (fp32 VALU GEMM) ----------------
__global__ __launch_bounds__(256) void proj_kernel(
    const float* __restrict__ query,
    const float* __restrict__ Wq, const float* __restrict__ Wk, const float* __restrict__ Wv,
    unsigned short* __restrict__ Qhi, unsigned short* __restrict__ Qlo,
    unsigned short* __restrict__ Khi, unsigned short* __restrict__ Klo,
    unsigned short* __restrict__ Vt)
{
    const int z = blockIdx.z;
    const float* W = (z == 0) ? Wq : (z == 1) ? Wk : Wv;
    const int m0 = blockIdx.x * 64;
    const int n0 = blockIdx.y * 64;
    __shared__ float xs[64 * 68];
    __shared__ float ws[64 * 68];
    const int t = threadIdx.x;
    const int ty = t >> 4, tx = t & 15;
    float acc[4][4] = {};
    for (int kc = 0; kc < 128; kc += 64) {
        #pragma unroll
        for (int it = 0; it < 4; ++it) {
            int fi = t + it * 256;
            int row = fi >> 4, c4 = fi & 15;
            *(float4*)(&xs[row * 68 + c4 * 4]) = *(const float4*)(&query[(size_t)(m0 + row) * 128 + kc + c4 * 4]);
            *(float4*)(&ws[row * 68 + c4 * 4]) = *(const float4*)(&W[(size_t)(n0 + row) * 128 + kc + c4 * 4]);
        }
        __syncthreads();
        #pragma unroll
        for (int k4 = 0; k4 < 16; ++k4) {
            float4 a4[4], b4[4];
            #pragma unroll
            for (int i = 0; i < 4; ++i) a4[i] = *(const float4*)(&xs[(ty * 4 + i) * 68 + k4 * 4]);
            #pragma unroll
            for (int j = 0; j < 4; ++j) b4[j] = *(const float4*)(&ws[(tx * 4 + j) * 68 + k4 * 4]);
            #pragma unroll
            for (int i = 0; i < 4; ++i)
                #pragma unroll
                for (int j = 0; j < 4; ++j)
                    acc[i][j] += a4[i].x * b4[j].x + a4[i].y * b4[j].y + a4[i].z * b4[j].z + a4[i].w * b4[j].w;
        }
        __syncthreads();
    }
    #pragma unroll
    for (int i = 0; i < 4; ++i) {
        int m = m0 + ty * 4 + i;
        int b = m >> 10, s = m & 1023;
        #pragma unroll
        for (int j = 0; j < 4; ++j) {
            int o = n0 + tx * 4 + j;
            int h = o >> 5, d = o & 31;
            int bh = b * 8 + h;
            float y = acc[i][j];
            if (z < 2) {
                unsigned short hi = f2bf(y);
                unsigned short lo = f2bf(y - bf2f(hi));
                size_t idx = ((size_t)(bh * 1024 + s)) * 32 + d;
                if (z == 0) { Qhi[idx] = hi; Qlo[idx] = lo; }
                else        { Khi[idx] = hi; Klo[idx] = lo; }
            } else {
                Vt[((size_t)(bh * 32 + d)) * 1024 + s] = f2bf(y);
            }
        }
    }
}

// ---------------- Kernel 1b: mask bias from Q row sums ----------------
__global__ void mask_kernel(const unsigned short* __restrict__ Qhi,
                            const unsigned short* __restrict__ Qlo,
                            float* __restrict__ maskbias)
{
    int r = blockIdx.x * blockDim.x + threadIdx.x;
    if (r >= BH_ * S_) return;
    const unsigned short* ph = Qhi + (size_t)r * 32;
    const unsigned short* pl = Qlo + (size_t)r * 32;
    float s = 0.f;
    #pragma unroll
    for (int d = 0; d < 32; ++d) s += bf2f(ph[d]) + bf2f(pl[d]);
    maskbias[r] = (s != 0.0f) ? 0.0f : -INFINITY;
}

// ---------------- Kernel 2: fused attention (swapped-operand layout) ----------------
// grid 4096 = 64 (b,h) x 64 q-tiles of 16 rows; block 256 = 4 waves.
// Wave w owns key strip [256w, 256w+256). QK^T computed SWAPPED: mfma(K, Q)
// so C = S^T[k][q]: lane holds q = c (lane&15), k = kstrip + kf*16 + g*4 + r.
// => U loads / maskbias loads / attn stores are all float4 along k.
// Softmax: in-lane reduce over kf,r; shfl_xor(16,32) across g; 4-wave LDS reduce.
// P packed bf16 (truncated) into LDS [16 q][516 u32-pairs]; PV swapped too:
// O^T = mfma(V^T-frag from Vt, P-frag from LDS); 2-way k-half reduce in LDS.
#define P32_STRIDE 516
#define LDS_P_BYTES (16 * P32_STRIDE * 4)        // 33024
#define LDS_ORED_BYTES (2 * 16 * 36 * 4)         // 4608
#define ATTN_LDS (LDS_P_BYTES + LDS_ORED_BYTES + 2 * 64 * 4)

__global__ __launch_bounds__(256, 3) void attn_kernel(
    const unsigned short* __restrict__ Qhi, const unsigned short* __restrict__ Qlo,
    const unsigned short* __restrict__ Khi, const unsigned short* __restrict__ Klo,
    const unsigned short* __restrict__ Vt, const float* __restrict__ maskbias,
    const float* __restrict__ U, float* __restrict__ attn_out, float* __restrict__ out_buf)
{
    extern __shared__ unsigned char lds_raw[];
    unsigned int* P32 = (unsigned int*)lds_raw;                      // [16][516]
    float* Ored = (float*)(lds_raw + LDS_P_BYTES);                   // [2][16][36]
    float* redm = (float*)(lds_raw + LDS_P_BYTES + LDS_ORED_BYTES);  // [4][16]
    float* reds = redm + 64;                                         // [4][16]

    const int bh = blockIdx.x >> 6;
    const int qbase = (blockIdx.x & 63) << 4;
    const int tid = threadIdx.x;
    const int wid = tid >> 6;
    const int c = tid & 15;
    const int g = (tid >> 4) & 3;
    const int kstrip = wid << 8;

    const size_t bh_qk = (size_t)bh * S_ * 32;
    const size_t bh_u = (size_t)bh * S_ * S_;
    const int q = qbase + c;

    // Q fragment (B operand: row = q = c, cols d = g*8..g*8+7)
    short8 qh = *(const short8*)(Qhi + bh_qk + (size_t)q * 32 + 8 * g);
    short8 ql = *(const short8*)(Qlo + bh_qk + (size_t)q * 32 + 8 * g);

    f32x4 s[16];
    #pragma unroll
    for (int kf = 0; kf < 16; ++kf) s[kf] = (f32x4){0.f, 0.f, 0.f, 0.f};

    // QK^T swapped: A = K (rows k), B = Q (rows q); hi/lo split (3 MFMAs)
    #pragma unroll
    for (int kf = 0; kf < 16; ++kf) {
        size_t koff = bh_qk + (size_t)(kstrip + kf * 16 + c) * 32 + 8 * g;
        short8 kh = *(const short8*)(Khi + koff);
        short8 kl = *(const short8*)(Klo + koff);
        s[kf] = __builtin_amdgcn_mfma_f32_16x16x32_bf16(kh, qh, s[kf], 0, 0, 0);
        s[kf] = __builtin_amdgcn_mfma_f32_16x16x32_bf16(kl, qh, s[kf], 0, 0, 0);
        s[kf] = __builtin_amdgcn_mfma_f32_16x16x32_bf16(kh, ql, s[kf], 0, 0, 0);
    }

    const float inv_scale = 0.17677669529663687f; // 1/sqrt(32)
    const float* Urow = U + bh_u + (size_t)q * S_;
    const float* mbrow = maskbias + bh * S_;
    #pragma unroll
    for (int kf = 0; kf < 16; ++kf) {
        int k0 = kstrip + kf * 16 + g * 4;
        f32x4 u = *(const f32x4*)(Urow + k0);
        f32x4 mb = *(const f32x4*)(mbrow + k0);
        #pragma unroll
        for (int r = 0; r < 4; ++r)
            s[kf][r] = (s[kf][r] + u[r]) * inv_scale + mb[r];
    }

    // row max: in-lane, then across g groups (lanes c, c+16, c+32, c+48)
    float m = s[0][0];
    #pragma unroll
    for (int kf = 0; kf < 16; ++kf)
        #pragma unroll
        for (int r = 0; r < 4; ++r) m = fmaxf(m, s[kf][r]);
    m = fmaxf(m, __shfl_xor(m, 16, 64));
    m = fmaxf(m, __shfl_xor(m, 32, 64));
    if (g == 0) redm[wid * 16 + c] = m;
    __syncthreads();
    const float gm = fmaxf(fmaxf(redm[c], redm[16 + c]), fmaxf(redm[32 + c], redm[48 + c]));

    // exp & sum
    float sum = 0.f;
    #pragma unroll
    for (int kf = 0; kf < 16; ++kf)
        #pragma unroll
        for (int r = 0; r < 4; ++r) {
            float p = __expf(s[kf][r] - gm);
            s[kf][r] = p;
            sum += p;
        }
    sum += __shfl_xor(sum, 16, 64);
    sum += __shfl_xor(sum, 32, 64);
    if (g == 0) reds[wid * 16 + c] = sum;
    __syncthreads();
    const float inv = 1.0f / (reds[c] + reds[16 + c] + reds[32 + c] + reds[48 + c]);

    // normalize: float4 attn store + packed-bf16 P to LDS
    float* arow = attn_out + bh_u + (size_t)q * S_;
    #pragma unroll
    for (int kf = 0; kf < 16; ++kf) {
        int k0 = kstrip + kf * 16 + g * 4;
        f32x4 a;
        #pragma unroll
        for (int r = 0; r < 4; ++r) a[r] = s[kf][r] * inv;
        *(f32x4*)(arow + k0) = a;
        // truncate-pack 2x2 f32 -> bf16 pairs (1 v_perm each)
        unsigned int w0 = __builtin_amdgcn_perm(__float_as_uint(a[1]), __float_as_uint(a[0]), 0x07060302u);
        unsigned int w1 = __builtin_amdgcn_perm(__float_as_uint(a[3]), __float_as_uint(a[2]), 0x07060302u);
        u32x2 pw = {w0, w1};
        *(u32x2*)(P32 + c * P32_STRIDE + (k0 >> 1)) = pw;
    }
    __syncthreads();

    // PV swapped: wave -> (df = wid&1 d-half, kh2 = wid>>1 k-half)
    const int df = wid & 1, kh2 = wid >> 1;
    f32x4 o = (f32x4){0.f, 0.f, 0.f, 0.f};
    const unsigned short* vb = Vt + (size_t)(bh * 32 + df * 16 + c) * S_ + kh2 * 512;
    const unsigned int* prow = P32 + c * P32_STRIDE + kh2 * 256;
    #pragma unroll
    for (int ch = 0; ch < 16; ++ch) {
        short8 A = *(const short8*)(vb + ch * 32 + g * 8);      // V^T rows d=c, k cols
        u32x4 braw = *(const u32x4*)(prow + ch * 16 + g * 4);   // P rows q=c, k cols
        short8 Bf;
        #pragma unroll
        for (int j = 0; j < 4; ++j) {
            Bf[2 * j] = (short)(braw[j] & 0xFFFFu);
            Bf[2 * j + 1] = (short)(braw[j] >> 16);
        }
        o = __builtin_amdgcn_mfma_f32_16x16x32_bf16(A, Bf, o, 0, 0, 0);
    }
    // partial O^T: lane holds d = df*16 + g*4 + r, q = c
    *(f32x4*)(&Ored[(kh2 * 16 + c) * 36 + df * 16 + g * 4]) = o;
    __syncthreads();

    // final 2-way reduce + store: thread t -> q = t>>4, d-pair = (t&15)*2
    const int qq = tid >> 4;
    const int dd = (tid & 15) * 2;
    float v0 = Ored[qq * 36 + dd] + Ored[(16 + qq) * 36 + dd];
    float v1 = Ored[qq * 36 + dd + 1] + Ored[(16 + qq) * 36 + dd + 1];
    const int b = bh >> 3, h = bh & 7;
    f32x2 vv = {v0, v1};
    *(f32x2*)(out_buf + ((size_t)(b * 1024 + qbase + qq)) * 256 + h * 32 + dd) = vv;
}

// ---------------- Kernel 3: output projection ----------------
__global__ __launch_bounds__(256) void outproj_kernel(
    const float* __restrict__ xb, const float* __restrict__ Wo, float* __restrict__ outp)
{
    const int m0 = blockIdx.x * 64;
    const int n0 = blockIdx.y * 64;
    __shared__ float xs[64 * 68];
    __shared__ float ws[64 * 68];
    const int t = threadIdx.x;
    const int ty = t >> 4, tx = t & 15;
    float acc[4][4] = {};
    for (int kc = 0; kc < 256; kc += 64) {
        #pragma unroll
        for (int it = 0; it < 4; ++it) {
            int fi = t + it * 256;
            int row = fi >> 4, c4 = fi & 15;
            *(float4*)(&xs[row * 68 + c4 * 4]) = *(const float4*)(&xb[(size_t)(m0 + row) * 256 + kc + c4 * 4]);
            *(float4*)(&ws[row * 68 + c4 * 4]) = *(const float4*)(&Wo[(size_t)(n0 + row) * 256 + kc + c4 * 4]);
        }
        __syncthreads();
        #pragma unroll
        for (int k4 = 0; k4 < 16; ++k4) {
            float4 a4[4], b4[4];
            #pragma unroll
            for (int i = 0; i < 4; ++i) a4[i] = *(const float4*)(&xs[(ty * 4 + i) * 68 + k4 * 4]);
            #pragma unroll
            for (int j = 0; j < 4; ++j) b4[j] = *(const float4*)(&ws[(tx * 4 + j) * 68 + k4 * 4]);
            #pragma unroll
            for (int i = 0; i < 4; ++i)
                #pragma unroll
                for (int j = 0; j < 4; ++j)
                    acc[i][j] += a4[i].x * b4[j].x + a4[i].y * b4[j].y + a4[i].z * b4[j].z + a4[i].w * b4[j].w;
        }
        __syncthreads();
    }
    #pragma unroll
    for (int i = 0; i < 4; ++i)
        #pragma unroll
        for (int j = 0; j < 4; ++j)
            outp[(size_t)(m0 + ty * 4 + i) * 128 + n0 + tx * 4 + j] = acc[i][j];
}

extern "C" void kernel_launch(void* const* d_in, const int* in_sizes, int n_in,
                              void* d_out, int out_size, void* d_ws, size_t ws_size,
                              hipStream_t stream)
{
    const float* query = (const float*)d_in[0];
    const float* U     = (const float*)d_in[1];
    const float* Wq    = (const float*)d_in[2];
    const float* Wk    = (const float*)d_in[3];
    const float* Wv    = (const float*)d_in[4];
    const float* Wo    = (const float*)d_in[5];

    float* output = (float*)d_out;                                 // B*S*D0
    float* attn   = (float*)d_out + (size_t)B_ * S_ * D0_;         // B*H*S*S

    const size_t NQK = (size_t)BH_ * S_ * 32;
    unsigned short* Qhi = (unsigned short*)d_ws;
    unsigned short* Qlo = Qhi + NQK;
    unsigned short* Khi = Qlo + NQK;
    unsigned short* Klo = Khi + NQK;
    unsigned short* Vt  = Klo + NQK;
    float* maskbias = (float*)(Vt + NQK);
    float* out_buf  = maskbias + (size_t)BH_ * S_;

    proj_kernel<<<dim3(128, 4, 3), 256, 0, stream>>>(query, Wq, Wk, Wv, Qhi, Qlo, Khi, Klo, Vt);
    mask_kernel<<<dim3(256), 256, 0, stream>>>(Qhi, Qlo, maskbias);

    hipFuncSetAttribute(reinterpret_cast<const void*>(attn_kernel),
                        hipFuncAttributeMaxDynamicSharedMemorySize, ATTN_LDS);
    attn_kernel<<<dim3(4096), 256, ATTN_LDS, stream>>>(Qhi, Qlo, Khi, Klo, Vt, maskbias, U, attn, out_buf);

    outproj_kernel<<<dim3(128, 2), 256, 0, stream>>>(out_buf, Wo, output);
}